// Round 3
// baseline (323.097 us; speedup 1.0000x reference)
//
#include <hip/hip_runtime.h>
#include <hip/hip_bf16.h>
#include <cstddef>

// LabelAttention2: algebraic collapse.
//   scores[b,s] = dot(Q[b,s,:], w) + bias + mask*(-1e9)
//     w[c] = (sum_d Wq_w[d,c]*ksum[d])/16,  bias = dot(Wq_b,ksum)/16
//     ksum[d] = dot(sum_l K[l,:], Wk_w[d,:]) + 64*Wk_b[d]
//   attn = softmax_s(scores) per batch; context[b,:] = sum_s attn[b,s]*V[b,s,:]
// exp without max-subtraction is safe: scores ~ N(0,~3.3); masked rows -> 0.
// R3: latency-bound fix — 16 independent loads/thread in scores (was 28 VGPRs,
// serialized load->shuffle chains at 17% HBM), 8-deep batched loads in ctx.

#define B 8
#define S 4096
#define DQ 1024
#define H 256
#define L 64
#define RPB 16                 // rows per scores block
#define SC2 16                 // rows per ctx chunk
#define NSC2 (S / SC2)         // 256

// ---- precompute (tiny) ----

// ks_c[c] = sum_l K[l,c]            (grid 16 x 64)
__global__ void ksumc_kernel(const float* __restrict__ K, float* __restrict__ ks_c) {
    int c = blockIdx.x * 64 + threadIdx.x;
    float acc = 0.f;
#pragma unroll 8
    for (int l = 0; l < L; ++l) acc += K[l * DQ + c];
    ks_c[c] = acc;
}

// ksum[d] = dot(ks_c, Wk_w[d,:]) + 64*Wk_b[d]   (grid 64 x 256, wave per d)
__global__ void ksum_kernel(const float* __restrict__ Wk_w, const float* __restrict__ Wk_b,
                            const float* __restrict__ ks_c, float* __restrict__ ksum) {
    __shared__ float sv[DQ];
    for (int i = threadIdx.x; i < DQ; i += 256) sv[i] = ks_c[i];
    __syncthreads();
    int wave = threadIdx.x >> 6, lane = threadIdx.x & 63;
    int d = blockIdx.x * 4 + wave;
    const float* wr = Wk_w + (size_t)d * DQ;
    float acc = 0.f;
#pragma unroll
    for (int j = 0; j < 4; ++j) {
        int idx = j * 256 + lane * 4;
        float4 a = *(const float4*)(wr + idx);
        float4 b = *(const float4*)(sv + idx);
        acc += a.x * b.x + a.y * b.y + a.z * b.z + a.w * b.w;
    }
    for (int off = 32; off; off >>= 1) acc += __shfl_down(acc, off);
    if (lane == 0) ksum[d] = acc + 64.f * Wk_b[d];
}

// blocks 0..15: w[c]; block 16: bias
__global__ void wvec_bias_kernel(const float* __restrict__ Wq_w, const float* __restrict__ Wq_b,
                                 const float* __restrict__ ksum, float* __restrict__ w,
                                 float* __restrict__ bias) {
    __shared__ float ks[H];
    __shared__ float red[4][64];
    __shared__ float red2[4];
    ks[threadIdx.x] = ksum[threadIdx.x];
    __syncthreads();
    int wave = threadIdx.x >> 6, lane = threadIdx.x & 63;
    if (blockIdx.x < 16) {
        int c = blockIdx.x * 64 + lane;
        float acc = 0.f;
#pragma unroll 8
        for (int j = 0; j < 64; ++j) {
            int d = wave + 4 * j;
            acc += Wq_w[(size_t)d * DQ + c] * ks[d];
        }
        red[wave][lane] = acc;
        __syncthreads();
        if (wave == 0)
            w[c] = (red[0][lane] + red[1][lane] + red[2][lane] + red[3][lane]) * 0.0625f;
    } else {
        float v = Wq_b[threadIdx.x] * ks[threadIdx.x];
        for (int off = 32; off; off >>= 1) v += __shfl_down(v, off);
        if (lane == 0) red2[wave] = v;
        __syncthreads();
        if (threadIdx.x == 0)
            bias[0] = (red2[0] + red2[1] + red2[2] + red2[3]) * 0.0625f;
    }
}

// ---- scores: grid 2048 x 256, 16 rows/block, 16 loads in flight per thread ----
__global__ __launch_bounds__(256) void scores_kernel(
        const float* __restrict__ Q, const float* __restrict__ w,
        const float* __restrict__ bias, const int* __restrict__ mask,
        float* __restrict__ escore, float* __restrict__ denom) {
    int t = threadIdx.x;
    size_t base = (size_t)blockIdx.x * RPB;            // flat row base; b uniform per block
    float4 wv = *(const float4*)(w + t * 4);
    __shared__ float sp[RPB * 256];
    __shared__ float bsum[RPB];
    const float* qb = Q + base * DQ + t * 4;

    float4 qv[RPB];
#pragma unroll
    for (int r = 0; r < RPB; ++r) qv[r] = *(const float4*)(qb + (size_t)r * DQ);
#pragma unroll
    for (int r = 0; r < RPB; ++r)
        sp[r * 256 + t] = qv[r].x * wv.x + qv[r].y * wv.y + qv[r].z * wv.z + qv[r].w * wv.w;
    __syncthreads();

    int r = t >> 4, j = t & 15;
    float s = 0.f;
#pragma unroll
    for (int k = 0; k < 16; ++k) s += sp[r * 256 + k * 16 + j];   // stride-16: conflict-free
    s += __shfl_xor(s, 8, 64);
    s += __shfl_xor(s, 4, 64);
    s += __shfl_xor(s, 2, 64);
    s += __shfl_xor(s, 1, 64);
    if (j == 0) {
        size_t row = base + r;
        float e = mask[row] ? 0.f : __expf(s + bias[0]);
        escore[row] = e;
        bsum[r] = e;
    }
    __syncthreads();
    if (t == 0) {
        float d0 = 0.f;
#pragma unroll
        for (int k = 0; k < RPB; ++k) d0 += bsum[k];
        atomicAdd(denom + (base >> 12), d0);
    }
}

// ---- ctx partial: grid {256,8} x 256, 16 rows/chunk, 8-deep load batches ----
__global__ __launch_bounds__(256) void ctx_partial_kernel(
        const float* __restrict__ V, const float* __restrict__ escore,
        float* __restrict__ partial) {
    int sc = blockIdx.x, b = blockIdx.y, t = threadIdx.x;
    __shared__ float es[SC2];
    if (t < SC2) es[t] = escore[(size_t)b * S + sc * SC2 + t];
    __syncthreads();
    const float* vb = V + ((size_t)b * S + (size_t)sc * SC2) * DQ + t * 4;
    float4 acc = {0.f, 0.f, 0.f, 0.f};
#pragma unroll
    for (int s0 = 0; s0 < SC2; s0 += 8) {
        float4 v[8];
#pragma unroll
        for (int k = 0; k < 8; ++k) v[k] = *(const float4*)(vb + (size_t)(s0 + k) * DQ);
#pragma unroll
        for (int k = 0; k < 8; ++k) {
            float a = es[s0 + k];
            acc.x += a * v[k].x; acc.y += a * v[k].y;
            acc.z += a * v[k].z; acc.w += a * v[k].w;
        }
    }
    *(float4*)(partial + ((size_t)b * NSC2 + sc) * DQ + t * 4) = acc;
}

// blocks 0..127: attn = escore/denom[b]; blocks 128..159: ctx reduce
__global__ void epilogue_kernel(const float* __restrict__ escore, const float* __restrict__ partial,
                                const float* __restrict__ denom,
                                float* __restrict__ ctx, float* __restrict__ attn) {
    if (blockIdx.x < 128) {
        int i = blockIdx.x * 256 + threadIdx.x;            // 0..32767
        attn[i] = escore[i] / denom[i >> 12];
    } else {
        int idx = (blockIdx.x - 128) * 256 + threadIdx.x;  // 0..8191
        int b = idx >> 10, d = idx & 1023;
        const float* p = partial + (size_t)b * NSC2 * DQ + d;
        float acc = 0.f;
#pragma unroll 8
        for (int sc = 0; sc < NSC2; ++sc) acc += p[(size_t)sc * DQ];
        ctx[idx] = acc / denom[b];
    }
}

extern "C" void kernel_launch(void* const* d_in, const int* in_sizes, int n_in,
                              void* d_out, int out_size, void* d_ws, size_t ws_size,
                              hipStream_t stream) {
    const float* Q    = (const float*)d_in[0];
    const float* K    = (const float*)d_in[1];
    const float* V    = (const float*)d_in[2];
    const int*   mask = (const int*)d_in[3];
    const float* Wq_w = (const float*)d_in[4];
    const float* Wq_b = (const float*)d_in[5];
    const float* Wk_w = (const float*)d_in[6];
    const float* Wk_b = (const float*)d_in[7];

    float* ws     = (float*)d_ws;
    float* ks_c   = ws;                  // 1024
    float* ksum   = ws + 1024;           // 256
    float* wv     = ws + 1280;           // 1024
    float* bias   = ws + 2304;           // 1
    float* denom  = ws + 2312;           // 8
    float* escore = ws + 4096;           // 32768
    float* partial = ws + 4096 + B * S;  // 8*256*1024 floats = 8 MB, 16B aligned

    float* ctx  = (float*)d_out;            // 8*1024
    float* attn = (float*)d_out + B * DQ;   // 8*4096

    hipMemsetAsync(denom, 0, B * sizeof(float), stream);
    ksumc_kernel<<<16, 64, 0, stream>>>(K, ks_c);
    ksum_kernel<<<H / 4, 256, 0, stream>>>(Wk_w, Wk_b, ks_c, ksum);
    wvec_bias_kernel<<<17, 256, 0, stream>>>(Wq_w, Wq_b, ksum, wv, bias);
    scores_kernel<<<(B * S) / RPB, 256, 0, stream>>>(Q, wv, bias, mask, escore, denom);
    ctx_partial_kernel<<<dim3(NSC2, B), 256, 0, stream>>>(V, escore, partial);
    epilogue_kernel<<<160, 256, 0, stream>>>(escore, partial, denom, ctx, attn);
}

// Round 4
// 319.326 us; speedup vs baseline: 1.0118x; 1.0118x over previous
//
#include <hip/hip_runtime.h>
#include <hip/hip_bf16.h>
#include <cstddef>

// LabelAttention2: algebraic collapse.
//   scores[b,s] = dot(Q[b,s,:], w) + bias + mask*(-1e9)
//     w[c] = (sum_d Wq_w[d,c]*ksum[d])/16,  bias = dot(Wq_b,ksum)/16
//     ksum[d] = dot(sum_l K[l,:], Wk_w[d,:]) + 64*Wk_b[d]
//   attn = softmax_s(scores) per batch; context[b,:] = sum_s attn[b,s]*V[b,s,:]
// exp without max-subtraction is safe: scores ~ N(0,~3.3), max |s| << 88;
// masked rows -> exactly 0 (matches reference underflow).
// R4: fuse to 4 graph nodes; fused main = 16 indep Q-loads/thread + LDS
// transpose-reduce + 8-deep V batches, so it's top-dispatch-visible again.

#define B 8
#define S 4096
#define DQ 1024
#define H 256
#define L 64
#define RPB 16                 // rows per fused block
#define NSC (S / RPB)          // 256 chunks per batch

// ---- pre1: ksum[d] = dot(sum_l K[l,:], Wk_w[d,:]) + 64*Wk_b[d]  (grid 64 x 256)
//      each block recomputes the K column-sum (256 KB, L2/L3-cached); block 0
//      also zeroes denom (runs before fused_main's atomics).
__global__ __launch_bounds__(256) void pre1_kernel(
        const float* __restrict__ K, const float* __restrict__ Wk_w,
        const float* __restrict__ Wk_b, float* __restrict__ ksum,
        float* __restrict__ denom) {
    __shared__ float sv[DQ];
    int t = threadIdx.x;
    if (blockIdx.x == 0 && t < B) denom[t] = 0.f;
    float4 a = {0.f, 0.f, 0.f, 0.f};
    const float* kp = K + t * 4;
#pragma unroll 8
    for (int l = 0; l < L; ++l) {
        float4 k = *(const float4*)(kp + (size_t)l * DQ);
        a.x += k.x; a.y += k.y; a.z += k.z; a.w += k.w;
    }
    *(float4*)(sv + t * 4) = a;
    __syncthreads();
    int wave = t >> 6, lane = t & 63;
    int d = blockIdx.x * 4 + wave;
    const float* wr = Wk_w + (size_t)d * DQ;
    float acc = 0.f;
#pragma unroll
    for (int j = 0; j < 4; ++j) {
        int idx = j * 256 + lane * 4;
        float4 x = *(const float4*)(wr + idx);
        float4 y = *(const float4*)(sv + idx);
        acc += x.x * y.x + x.y * y.y + x.z * y.z + x.w * y.w;
    }
    for (int off = 32; off; off >>= 1) acc += __shfl_down(acc, off);
    if (lane == 0) ksum[d] = acc + 64.f * Wk_b[d];
}

// ---- pre2: blocks 0..15: w[c] = (sum_d Wq_w[d,c]*ksum[d])/16; block 16: bias
__global__ __launch_bounds__(256) void pre2_kernel(
        const float* __restrict__ Wq_w, const float* __restrict__ Wq_b,
        const float* __restrict__ ksum, float* __restrict__ w,
        float* __restrict__ bias) {
    __shared__ float ks[H];
    __shared__ float red[4][64];
    __shared__ float red2[4];
    ks[threadIdx.x] = ksum[threadIdx.x];
    __syncthreads();
    int wave = threadIdx.x >> 6, lane = threadIdx.x & 63;
    if (blockIdx.x < 16) {
        int c = blockIdx.x * 64 + lane;
        float acc = 0.f;
#pragma unroll 8
        for (int j = 0; j < 64; ++j) {
            int d = wave + 4 * j;
            acc += Wq_w[(size_t)d * DQ + c] * ks[d];
        }
        red[wave][lane] = acc;
        __syncthreads();
        if (wave == 0)
            w[c] = (red[0][lane] + red[1][lane] + red[2][lane] + red[3][lane]) * 0.0625f;
    } else {
        float v = Wq_b[threadIdx.x] * ks[threadIdx.x];
        for (int off = 32; off; off >>= 1) v += __shfl_down(v, off);
        if (lane == 0) red2[wave] = v;
        __syncthreads();
        if (threadIdx.x == 0)
            bias[0] = (red2[0] + red2[1] + red2[2] + red2[3]) * 0.0625f;
    }
}

// ---- fused main: scores+exp+denom-atomic+weighted-V   (grid {256,8} x 256) ----
__global__ __launch_bounds__(256) void fused_main_kernel(
        const float* __restrict__ Q, const float* __restrict__ V,
        const float* __restrict__ w, const float* __restrict__ bias,
        const int* __restrict__ mask,
        float* __restrict__ escore, float* __restrict__ denom,
        float* __restrict__ partial) {
    int sc = blockIdx.x, b = blockIdx.y, t = threadIdx.x;
    __shared__ float sp[RPB * 256];
    __shared__ float es[RPB];
    size_t rowbase = (size_t)b * S + (size_t)sc * RPB;

    // phase 1: 16 independent float4 Q-loads per thread (MLP), dot with w
    const float* qb = Q + rowbase * DQ + t * 4;
    float4 wv = *(const float4*)(w + t * 4);
    float4 qv[RPB];
#pragma unroll
    for (int r = 0; r < RPB; ++r) qv[r] = *(const float4*)(qb + (size_t)r * DQ);
#pragma unroll
    for (int r = 0; r < RPB; ++r)
        sp[r * 256 + t] = qv[r].x * wv.x + qv[r].y * wv.y + qv[r].z * wv.z + qv[r].w * wv.w;
    __syncthreads();

    // transpose-reduce: thread (r=t>>4, j=t&15) sums 16 partials then shfl
    int r = t >> 4, j = t & 15;
    float s = 0.f;
#pragma unroll
    for (int k = 0; k < 16; ++k) s += sp[r * 256 + k * 16 + j];
    s += __shfl_xor(s, 8, 64);
    s += __shfl_xor(s, 4, 64);
    s += __shfl_xor(s, 2, 64);
    s += __shfl_xor(s, 1, 64);
    if (j == 0) {
        size_t row = rowbase + r;
        float e = mask[row] ? 0.f : __expf(s + bias[0]);
        es[r] = e;
        escore[row] = e;
    }
    __syncthreads();
    if (t == 0) {
        float d0 = 0.f;
#pragma unroll
        for (int k = 0; k < RPB; ++k) d0 += es[k];
        atomicAdd(denom + b, d0);
    }

    // phase 2: weighted V partial, 8-deep independent load batches
    const float* vb = V + rowbase * DQ + t * 4;
    float4 acc = {0.f, 0.f, 0.f, 0.f};
#pragma unroll
    for (int s0 = 0; s0 < RPB; s0 += 8) {
        float4 v[8];
#pragma unroll
        for (int k = 0; k < 8; ++k) v[k] = *(const float4*)(vb + (size_t)(s0 + k) * DQ);
#pragma unroll
        for (int k = 0; k < 8; ++k) {
            float a = es[s0 + k];
            acc.x += a * v[k].x; acc.y += a * v[k].y;
            acc.z += a * v[k].z; acc.w += a * v[k].w;
        }
    }
    *(float4*)(partial + ((size_t)b * NSC + sc) * DQ + t * 4) = acc;
}

// ---- epilogue: blocks 0..127 attn = escore/denom[b]; 128..159 ctx reduce ----
__global__ __launch_bounds__(256) void epilogue_kernel(
        const float* __restrict__ escore, const float* __restrict__ partial,
        const float* __restrict__ denom,
        float* __restrict__ ctx, float* __restrict__ attn) {
    if (blockIdx.x < 128) {
        int i = blockIdx.x * 256 + threadIdx.x;            // 0..32767
        attn[i] = escore[i] / denom[i >> 12];
    } else {
        int idx = (blockIdx.x - 128) * 256 + threadIdx.x;  // 0..8191
        int b = idx >> 10, d = idx & 1023;
        const float* p = partial + (size_t)b * NSC * DQ + d;
        float acc = 0.f;
#pragma unroll 8
        for (int sc = 0; sc < NSC; ++sc) acc += p[(size_t)sc * DQ];
        ctx[idx] = acc / denom[b];
    }
}

extern "C" void kernel_launch(void* const* d_in, const int* in_sizes, int n_in,
                              void* d_out, int out_size, void* d_ws, size_t ws_size,
                              hipStream_t stream) {
    const float* Q    = (const float*)d_in[0];
    const float* K    = (const float*)d_in[1];
    const float* V    = (const float*)d_in[2];
    const int*   mask = (const int*)d_in[3];
    const float* Wq_w = (const float*)d_in[4];
    const float* Wq_b = (const float*)d_in[5];
    const float* Wk_w = (const float*)d_in[6];
    const float* Wk_b = (const float*)d_in[7];

    float* ws     = (float*)d_ws;
    float* ksum   = ws;                  // 256
    float* wv     = ws + 256;            // 1024
    float* bias   = ws + 1280;           // 1
    float* denom  = ws + 1288;           // 8
    float* escore = ws + 4096;           // 32768
    float* partial = ws + 4096 + B * S;  // 8*256*1024 floats = 8 MB, 16B aligned

    float* ctx  = (float*)d_out;            // 8*1024
    float* attn = (float*)d_out + B * DQ;   // 8*4096

    pre1_kernel<<<H / 4, 256, 0, stream>>>(K, Wk_w, Wk_b, ksum, denom);
    pre2_kernel<<<17, 256, 0, stream>>>(Wq_w, Wq_b, ksum, wv, bias);
    fused_main_kernel<<<dim3(NSC, B), 256, 0, stream>>>(Q, V, wv, bias, mask,
                                                        escore, denom, partial);
    epilogue_kernel<<<160, 256, 0, stream>>>(escore, partial, denom, ctx, attn);
}

// Round 5
// 313.542 us; speedup vs baseline: 1.0305x; 1.0184x over previous
//
#include <hip/hip_runtime.h>
#include <hip/hip_bf16.h>
#include <cstddef>

// LabelAttention2: algebraic collapse.
//   scores[b,s] = dot(Q[b,s,:], w) + bias + mask*(-1e9)
//     w[c] = (sum_d Wq_w[d,c]*ksum[d])/16,  bias = dot(Wq_b,ksum)/16
//     ksum[d] = dot(sum_l K[l,:], Wk_w[d,:]) + 64*Wk_b[d]
//   attn = softmax_s(scores) per batch; context[b,:] = sum_s attn[b,s]*V[b,s,:]
// exp without max-subtraction is safe: scores ~ N(0,~3.3); masked rows -> 0.
// R5: kill the burst/stall phase structure. Private-w trick (each thread's w
// chunk is loop-invariant -> registers), acc[] arrays force live VGPRs, hand
// software-pipelined 8-batches, single reduce tail per block.

#define B 8
#define S 4096
#define DQ 1024
#define H 256
#define L 64
#define SRPB 16                // rows per scores block (2048 blocks)
#define CRPB 32                // rows per ctx block   (1024 blocks)
#define NCHUNK (S / CRPB)      // 128 partial chunks per batch

// ---- pre1: ksum[d] = dot(sum_l K[l,:], Wk_w[d,:]) + 64*Wk_b[d]  (64 x 256)
__global__ __launch_bounds__(256) void pre1_kernel(
        const float* __restrict__ K, const float* __restrict__ Wk_w,
        const float* __restrict__ Wk_b, float* __restrict__ ksum,
        float* __restrict__ denom) {
    __shared__ float sv[DQ];
    int t = threadIdx.x;
    if (blockIdx.x == 0 && t < B) denom[t] = 0.f;
    float4 a = {0.f, 0.f, 0.f, 0.f};
    const float* kp = K + t * 4;
#pragma unroll 8
    for (int l = 0; l < L; ++l) {
        float4 k = *(const float4*)(kp + (size_t)l * DQ);
        a.x += k.x; a.y += k.y; a.z += k.z; a.w += k.w;
    }
    *(float4*)(sv + t * 4) = a;
    __syncthreads();
    int wave = t >> 6, lane = t & 63;
    int d = blockIdx.x * 4 + wave;
    const float* wr = Wk_w + (size_t)d * DQ;
    float acc = 0.f;
#pragma unroll
    for (int j = 0; j < 4; ++j) {
        int idx = j * 256 + lane * 4;
        float4 x = *(const float4*)(wr + idx);
        float4 y = *(const float4*)(sv + idx);
        acc += x.x * y.x + x.y * y.y + x.z * y.z + x.w * y.w;
    }
    for (int off = 32; off; off >>= 1) acc += __shfl_down(acc, off);
    if (lane == 0) ksum[d] = acc + 64.f * Wk_b[d];
}

// ---- pre2: blocks 0..15: w[c]; block 16: bias ----
__global__ __launch_bounds__(256) void pre2_kernel(
        const float* __restrict__ Wq_w, const float* __restrict__ Wq_b,
        const float* __restrict__ ksum, float* __restrict__ w,
        float* __restrict__ bias) {
    __shared__ float ks[H];
    __shared__ float red[4][64];
    __shared__ float red2[4];
    ks[threadIdx.x] = ksum[threadIdx.x];
    __syncthreads();
    int wave = threadIdx.x >> 6, lane = threadIdx.x & 63;
    if (blockIdx.x < 16) {
        int c = blockIdx.x * 64 + lane;
        float acc = 0.f;
#pragma unroll 8
        for (int j = 0; j < 64; ++j) {
            int d = wave + 4 * j;
            acc += Wq_w[(size_t)d * DQ + c] * ks[d];
        }
        red[wave][lane] = acc;
        __syncthreads();
        if (wave == 0)
            w[c] = (red[0][lane] + red[1][lane] + red[2][lane] + red[3][lane]) * 0.0625f;
    } else {
        float v = Wq_b[threadIdx.x] * ks[threadIdx.x];
        for (int off = 32; off; off >>= 1) v += __shfl_down(v, off);
        if (lane == 0) red2[wave] = v;
        __syncthreads();
        if (threadIdx.x == 0)
            bias[0] = (red2[0] + red2[1] + red2[2] + red2[3]) * 0.0625f;
    }
}

// ---- scores: grid 2048 x 256. Thread t's w-chunk (float4 at 4t) is constant
// across its 16 rows -> registers; 16 independent loads, pipelined 8+8.
__global__ __launch_bounds__(256) void scores_kernel(
        const float* __restrict__ Q, const float* __restrict__ w,
        const float* __restrict__ bias, const int* __restrict__ mask,
        float* __restrict__ escore, float* __restrict__ denom) {
    int t = threadIdx.x, g = blockIdx.x;
    __shared__ float sp[SRPB][264];   // pad 264: reduce reads 2-way max
    __shared__ float sp2[SRPB];
    __shared__ int ml[SRPB];
    size_t rowbase = (size_t)g * SRPB;
    if (t < SRPB) ml[t] = mask[rowbase + t];
    float sb = bias[0];
    float4 wt = *(const float4*)(w + t * 4);
    const float* qb = Q + rowbase * DQ + t * 4;

    float4 buf[8], buf2[8];
#pragma unroll
    for (int k = 0; k < 8; ++k) buf[k] = *(const float4*)(qb + (size_t)k * DQ);
#pragma unroll
    for (int k = 0; k < 8; ++k) buf2[k] = *(const float4*)(qb + (size_t)(8 + k) * DQ);
    float acc[SRPB];
#pragma unroll
    for (int k = 0; k < 8; ++k)
        acc[k] = buf[k].x * wt.x + buf[k].y * wt.y + buf[k].z * wt.z + buf[k].w * wt.w;
#pragma unroll
    for (int k = 0; k < 8; ++k)
        acc[8 + k] = buf2[k].x * wt.x + buf2[k].y * wt.y + buf2[k].z * wt.z + buf2[k].w * wt.w;
#pragma unroll
    for (int r = 0; r < SRPB; ++r) sp[r][t] = acc[r];
    __syncthreads();

    int r = t >> 4, j = t & 15;
    float s = 0.f;
#pragma unroll
    for (int k = 0; k < 16; ++k) s += sp[r][k * 16 + j];
    s += __shfl_xor(s, 8, 64);
    s += __shfl_xor(s, 4, 64);
    s += __shfl_xor(s, 2, 64);
    s += __shfl_xor(s, 1, 64);
    if (j == 0) {
        float e = ml[r] ? 0.f : __expf(s + sb);
        sp2[r] = e;
        escore[rowbase + r] = e;
    }
    __syncthreads();
    if (t == 0) {
        float d0 = 0.f;
#pragma unroll
        for (int k = 0; k < SRPB; ++k) d0 += sp2[k];
        atomicAdd(denom + (g >> 8), d0);
    }
}

// ---- ctx: grid 1024 x 256, 32-row stream, hand-pipelined 8-batches ----
__global__ __launch_bounds__(256) void ctx_kernel(
        const float* __restrict__ V, const float* __restrict__ escore,
        float* __restrict__ partial) {
    int t = threadIdx.x, g = blockIdx.x;
    __shared__ float es[CRPB];
    size_t rowbase = (size_t)g * CRPB;
    if (t < CRPB) es[t] = escore[rowbase + t];
    __syncthreads();
    const float* vb = V + rowbase * DQ + t * 4;
    float4 acc = {0.f, 0.f, 0.f, 0.f};
    float4 buf[8];
#pragma unroll
    for (int k = 0; k < 8; ++k) buf[k] = *(const float4*)(vb + (size_t)k * DQ);
#pragma unroll
    for (int rb = 0; rb < CRPB; rb += 8) {
        float4 nbuf[8];
        if (rb + 8 < CRPB) {
#pragma unroll
            for (int k = 0; k < 8; ++k)
                nbuf[k] = *(const float4*)(vb + (size_t)(rb + 8 + k) * DQ);
        }
#pragma unroll
        for (int k = 0; k < 8; ++k) {
            float a = es[rb + k];
            acc.x += a * buf[k].x; acc.y += a * buf[k].y;
            acc.z += a * buf[k].z; acc.w += a * buf[k].w;
        }
#pragma unroll
        for (int k = 0; k < 8; ++k) buf[k] = nbuf[k];
    }
    *(float4*)(partial + (size_t)g * DQ + t * 4) = acc;
}

// ---- epilogue: blocks 0..127 attn = escore/denom[b]; 128..159 ctx reduce ----
__global__ __launch_bounds__(256) void epilogue_kernel(
        const float* __restrict__ escore, const float* __restrict__ partial,
        const float* __restrict__ denom,
        float* __restrict__ ctx, float* __restrict__ attn) {
    if (blockIdx.x < 128) {
        int i = blockIdx.x * 256 + threadIdx.x;            // 0..32767
        attn[i] = escore[i] / denom[i >> 12];
    } else {
        int idx = (blockIdx.x - 128) * 256 + threadIdx.x;  // 0..8191
        int b = idx >> 10, d = idx & 1023;
        const float* p = partial + (size_t)b * NCHUNK * DQ + d;
        float acc = 0.f;
#pragma unroll 8
        for (int k = 0; k < NCHUNK; ++k) acc += p[(size_t)k * DQ];
        ctx[idx] = acc / denom[b];
    }
}

extern "C" void kernel_launch(void* const* d_in, const int* in_sizes, int n_in,
                              void* d_out, int out_size, void* d_ws, size_t ws_size,
                              hipStream_t stream) {
    const float* Q    = (const float*)d_in[0];
    const float* K    = (const float*)d_in[1];
    const float* V    = (const float*)d_in[2];
    const int*   mask = (const int*)d_in[3];
    const float* Wq_w = (const float*)d_in[4];
    const float* Wq_b = (const float*)d_in[5];
    const float* Wk_w = (const float*)d_in[6];
    const float* Wk_b = (const float*)d_in[7];

    float* ws     = (float*)d_ws;
    float* ksum   = ws;                  // 256
    float* wv     = ws + 256;            // 1024
    float* bias   = ws + 1280;           // 1
    float* denom  = ws + 1288;           // 8
    float* escore = ws + 4096;           // 32768
    float* partial = ws + 4096 + B * S;  // 1024*1024 floats = 4 MB, 16B aligned

    float* ctx  = (float*)d_out;            // 8*1024
    float* attn = (float*)d_out + B * DQ;   // 8*4096

    pre1_kernel<<<H / 4, 256, 0, stream>>>(K, Wk_w, Wk_b, ksum, denom);
    pre2_kernel<<<17, 256, 0, stream>>>(Wq_w, Wq_b, ksum, wv, bias);
    scores_kernel<<<(B * S) / SRPB, 256, 0, stream>>>(Q, wv, bias, mask, escore, denom);
    ctx_kernel<<<(B * S) / CRPB, 256, 0, stream>>>(V, escore, partial);
    epilogue_kernel<<<160, 256, 0, stream>>>(escore, partial, denom, ctx, attn);
}